// Round 17
// baseline (352.620 us; speedup 1.0000x reference)
//
#include <hip/hip_runtime.h>
#include <hip/hip_fp8.h>
#include <cstdint>

typedef unsigned short u16;
typedef unsigned char u8;
typedef __attribute__((ext_vector_type(8))) short s16x8;
typedef __attribute__((ext_vector_type(4))) float f32x4;
typedef __attribute__((ext_vector_type(8))) unsigned short u16x8;
typedef __attribute__((ext_vector_type(4))) unsigned short u16x4;
typedef __attribute__((ext_vector_type(2))) long l64x2;

#define B_ 128
#define T_ 512
#define C_ 512
#define TC 262144

static __device__ __forceinline__ float bf2f(u16 u) {
  union { unsigned int i; float f; } v; v.i = ((unsigned int)u) << 16; return v.f;
}
static __device__ __forceinline__ u16 f2bf(float f) {
  union { float fv; unsigned int i; } v; v.fv = f;
  unsigned int r = (v.i + 0x7FFFu + ((v.i >> 16) & 1u)) >> 16;
  return (u16)r;
}
// HW packed f32x2 -> fp8x2 (OCP e4m3 on gfx950); low 16 bits valid.
static __device__ __forceinline__ unsigned int cvtpk_fp8(float a, float b) {
  unsigned int r;
  asm volatile("v_cvt_pk_fp8_f32 %0, %1, %2" : "=v"(r) : "v"(a), "v"(b));
  return r & 0xffffu;
}
// K-axis permutation for fp8 operands: within each 64B K-tile, 16B slot j
// holds k-groups (j, j+4) -> one ds_read_b128 yields both MFMA k-halves.
static __device__ __forceinline__ int kperm(int c) {
  return (c & ~63) | (((c >> 3) & 3) << 4) | (((c >> 5) & 1) << 3) | (c & 7);
}

// x*sigmoid(2z) form of tanh-GELU (passed with absmax 0.031).
static __device__ __forceinline__ float gelu_fast(float x) {
  float x2 = x * x;
  float arg = 1.5957691216057308f * x * fmaf(0.044715f, x2, 1.0f);
  return x / (1.0f + __expf(-arg));
}

#define GLD16(gp, lp) __builtin_amdgcn_global_load_lds( \
    (const __attribute__((address_space(1))) void*)(gp), \
    (__attribute__((address_space(3))) void*)(lp), 16, 0, 0)

// -- LN1 stats pass + bf16 inputs cache + (folded) weight conversions --------
// wm (tril) bf16 plain; w1/w2 fp8 K-PERMUTED.

__global__ __launch_bounds__(256)
void reduce_stats_kernel(const float* __restrict__ X, float2* __restrict__ partials,
                         u16* __restrict__ Xb,
                         const float* __restrict__ triu_W, u16* __restrict__ wmb,
                         const float* __restrict__ fc1_W, u8* __restrict__ w1f8,
                         const float* __restrict__ fc2_W, u8* __restrict__ w2f8) {
  const int b = blockIdx.y, blk = blockIdx.x, tid = threadIdx.x;
  const size_t gi = (size_t)b * TC + (size_t)blk * 2048 + (size_t)tid * 8;
  const float* p = X + gi;
  f32x4 v0 = *(const f32x4*)p;
  f32x4 v1 = *(const f32x4*)(p + 4);
  float s = 0.f, q = 0.f;
  u16x8 ob;
#pragma unroll
  for (int i = 0; i < 4; ++i) {
    s += v0[i] + v1[i]; q += v0[i] * v0[i] + v1[i] * v1[i];
    ob[i] = f2bf(v0[i]); ob[4 + i] = f2bf(v1[i]);
  }
  *(u16x8*)(Xb + gi) = ob;

  // folded weight prep
  const int flat = (b * 128 + blk) * 256 + tid;
  if (flat < T_ * T_) {
    const int sr = flat >> 9, tcol = flat & 511;
    wmb[flat] = f2bf(tcol <= sr ? triu_W[flat] : 0.f);
  }
  if (flat < C_ * C_) {
    const int e = flat * 2;
    float2 a1 = *(const float2*)(fc1_W + e);
    float2 a2 = *(const float2*)(fc2_W + e);
    const int r1 = e >> 9,  c1 = e & 511;     // w1: 1024 rows x 512 k
    const int r2 = e >> 10, c2 = e & 1023;    // w2: 512 rows x 1024 k
    *(u16*)(w1f8 + (size_t)r1 * 512 + kperm(c1))  = (u16)cvtpk_fp8(a1.x, a1.y);
    *(u16*)(w2f8 + (size_t)r2 * 1024 + kperm(c2)) = (u16)cvtpk_fp8(a2.x, a2.y);
  }

  for (int o = 32; o; o >>= 1) { s += __shfl_down(s, o); q += __shfl_down(q, o); }
  __shared__ float ss[4], qq[4];
  if ((tid & 63) == 0) { ss[tid >> 6] = s; qq[tid >> 6] = q; }
  __syncthreads();
  if (tid == 0)
    partials[(size_t)b * 128 + blk] =
        make_float2(ss[0] + ss[1] + ss[2] + ss[3], qq[0] + qq[1] + qq[2] + qq[3]);
}

// --- LN1 apply + transpose -> xT (bf16; stats finalized inline) ------------

__global__ __launch_bounds__(256)
void ln1_transpose_kernel(const u16* __restrict__ Xb, const float* __restrict__ W,
                          const float* __restrict__ Bv, const float2* __restrict__ partials,
                          u16* __restrict__ xT) {
  const int b = blockIdx.z;
  const int t0 = blockIdx.y * 64, c0 = blockIdx.x * 64;
  const int tid = threadIdx.x;
  __shared__ u16 tile[64][72];
  __shared__ float smu, srs;

  if (tid < 64) {
    float2 p0 = partials[(size_t)b * 128 + tid];
    float2 p1 = partials[(size_t)b * 128 + 64 + tid];
    float s = p0.x + p1.x, q = p0.y + p1.y;
    for (int o = 32; o; o >>= 1) { s += __shfl_down(s, o); q += __shfl_down(q, o); }
    if (tid == 0) {
      float mean = s * (1.f / (float)TC);
      float var = q * (1.f / (float)TC) - mean * mean;
      smu = mean; srs = rsqrtf(var + 1e-5f);
    }
  }
  __syncthreads();
  const float mu = smu, rs = srs;

  const int rr = tid >> 4;
  const int cc = (tid & 15) * 4;
#pragma unroll
  for (int i = 0; i < 4; ++i) {
    const int lt = i * 16 + rr;
    const size_t wi = (size_t)(t0 + lt) * C_ + c0 + cc;
    u16x4 xa = *(const u16x4*)(Xb + (size_t)b * TC + wi);
    f32x4 w = *(const f32x4*)(W + wi);
    f32x4 bb = *(const f32x4*)(Bv + wi);
#pragma unroll
    for (int j = 0; j < 4; ++j)
      tile[lt][cc + j] = f2bf((bf2f(xa[j]) - mu) * rs * w[j] + bb[j]);
  }
  __syncthreads();
  const int c = tid >> 2;
  const int tg = (tid & 3) * 16;
  u16 buf[16];
#pragma unroll
  for (int i = 0; i < 16; ++i) buf[i] = tile[tg + i][c];
  const size_t o = (size_t)b * TC + (size_t)(c0 + c) * T_ + t0 + tg;
  u16x8 o0, o1;
#pragma unroll
  for (int i = 0; i < 8; ++i) { o0[i] = buf[i]; o1[i] = buf[8 + i]; }
  *(u16x8*)(xT + o) = o0;
  *(u16x8*)(xT + o + 8) = o1;
}

// - LN2 apply (stats4 inline): writes ONLY x8 (fp8, K-permuted; fc1's A) ----
// fc2 recomputes LN2(s) inline in its epilogue, so no bf16 x2 buffer.

__global__ __launch_bounds__(256)
void ln2_apply_kernel(const u16* __restrict__ S, const float* __restrict__ W,
                      const float* __restrict__ Bv, const float2* __restrict__ partials2,
                      u8* __restrict__ x8) {
  const size_t i = ((size_t)blockIdx.x * 256 + threadIdx.x) * 8;
  const int b = (int)(i >> 18);
  const size_t r = i & (size_t)(TC - 1);
  float2 p0 = partials2[(size_t)b * 4 + 0];
  float2 p1 = partials2[(size_t)b * 4 + 1];
  float2 p2 = partials2[(size_t)b * 4 + 2];
  float2 p3 = partials2[(size_t)b * 4 + 3];
  float s = (p0.x + p1.x) + (p2.x + p3.x);
  float q = (p0.y + p1.y) + (p2.y + p3.y);
  const float mu = s * (1.f / (float)TC);
  const float rs = rsqrtf(q * (1.f / (float)TC) - mu * mu + 1e-5f);

  u16x8 sv = *(const u16x8*)(S + i);
  f32x4 w0 = *(const f32x4*)(W + r);
  f32x4 w1 = *(const f32x4*)(W + r + 4);
  f32x4 b0 = *(const f32x4*)(Bv + r);
  f32x4 b1 = *(const f32x4*)(Bv + r + 4);
  float v[8];
#pragma unroll
  for (int j = 0; j < 4; ++j) {
    v[j]     = (bf2f(sv[j])     - mu) * rs * w0[j] + b0[j];
    v[4 + j] = (bf2f(sv[4 + j]) - mu) * rs * w1[j] + b1[j];
  }
  uint2 pk;
  pk.x = cvtpk_fp8(v[0], v[1]) | (cvtpk_fp8(v[2], v[3]) << 16);
  pk.y = cvtpk_fp8(v[4], v[5]) | (cvtpk_fp8(v[6], v[7]) << 16);
  const size_t pi = (i & ~(size_t)63) | (size_t)(((i >> 3) & 3) << 4) | (size_t)(((i >> 5) & 1) << 3);
  *(uint2*)(x8 + pi) = pk;
}

// ------- BT-layout MFMA GEMM, 256x256, BK=64, 2-barrier counted-vmcnt -------
// MODE 0 (TriU, bf16): proven r9 path (0 bank conflicts). epilogue bf16
//   s = acc + inputs_bf16 + triu_b[row], fused per-block LN2 partial stats.
// MODE 1/2 (fp8): K-permuted operands (kperm), LDS 128 rows x 128B tile,
//   chunk XOR (lrow&7) — verified conflict-free (r15). One ds_read_b128 per
//   fragment = both k-halves. lgkmcnt(0) AFTER cluster-0 (only needed before
//   the barrier protecting STAGE_A overwrite) so reads overlap MFMA.
// MODE 1 epilogue: h = fp8(gelu(acc + fc1_b[col])), K-permuted.
// MODE 2 epilogue: out = acc + fc2_b[col] + LN2(s) computed INLINE
//   (mu/rs from 4 partials; ln2_w/ln2_b L2-resident).

template <int MODE>
__global__ __launch_bounds__(512, (MODE == 0) ? 1 : 2)
void gemm_bt_kernel(const void* __restrict__ Av, const void* __restrict__ Bmv,
                    int K, int lda, int ldb,
                    void* __restrict__ Cp, int ldc,
                    const float* __restrict__ bias,
                    const void* __restrict__ res,
                    long long strideB, long long strideC,
                    float2* __restrict__ stat_part,
                    const float* __restrict__ ln2w, const float* __restrict__ ln2b) {
  constexpr int TILE_U16 = (MODE == 0) ? 16384 : 8192;
  __shared__ u16 Asb[2 * TILE_U16];
  __shared__ u16 Bsb[2 * TILE_U16];
  __shared__ float rs_[8], rq_[8];
  const int tid = threadIdx.x;

  // --- XCD-aware bijective remap (nwg % 8 == 0 for all launches) ---
  const int nwg = gridDim.x;
  const int orig = blockIdx.x;
  const int swz = (orig & 7) * (nwg >> 3) + (orig >> 3);
  int bx, by, bz;
  if (MODE == 0) { bz = swz >> 2; by = (swz >> 1) & 1; bx = swz & 1; }
  else if (MODE == 1) { bz = 0; by = swz >> 2; bx = swz & 3; }
  else { bz = 0; by = swz >> 1; bx = swz & 1; }

  const int m0 = by * 256, n0 = bx * 256;
  int kTiles = K >> 6;
  if (MODE == 0) { const int need = (by + 1) * 4; if (need < kTiles) kTiles = need; }

  const int lane = tid & 63;
  const int wave = tid >> 6;
  const int wm = (wave >> 2) * 128;   // 2 wave-rows of 128
  const int wn = (wave & 3) * 64;     // 4 wave-cols of 64
  const int lr = lane & 15;
  const int kg = lane >> 4;

  f32x4 acc[8][4];
  const f32x4 zero = {0.f, 0.f, 0.f, 0.f};
#pragma unroll
  for (int m = 0; m < 8; ++m)
#pragma unroll
    for (int n = 0; n < 4; ++n) acc[m][n] = zero;

  if (MODE == 0) {
    // ---------------- bf16 path (r9, proven) ----------------
    const u16* A = (const u16*)Av;
    const u16* Bp = (const u16*)Bmv + (size_t)bz * (size_t)strideB;
    auto STAGE_A = [&](int t) {
      const int k0 = t << 6;
      const int d = (t & 1) * 16384;
#pragma unroll
      for (int p = 0; p < 4; ++p) {
        const int q = p * 512 + tid;
        const int r = q >> 3;
        const int kcs = (q & 7) ^ (r & 7);
        GLD16(A + (size_t)(m0 + r) * lda + k0 + (kcs << 3), &Asb[d + q * 8]);
      }
    };
    auto STAGE_B = [&](int t) {
      const int k0 = t << 6;
      const int d = (t & 1) * 16384;
#pragma unroll
      for (int p = 0; p < 4; ++p) {
        const int q = p * 512 + tid;
        const int r = q >> 3;
        const int kcs = (q & 7) ^ (r & 7);
        GLD16(Bp + (size_t)(n0 + r) * ldb + k0 + (kcs << 3), &Bsb[d + q * 8]);
      }
    };
    STAGE_A(0); STAGE_B(0); STAGE_A(1);
    for (int kt = 0; kt < kTiles; ++kt) {
      const int d = (kt & 1) * 16384;
      if (kt + 1 < kTiles) asm volatile("s_waitcnt vmcnt(4)" ::: "memory");
      else                 asm volatile("s_waitcnt vmcnt(0)" ::: "memory");
      __builtin_amdgcn_s_barrier();
      asm volatile("" ::: "memory");

      s16x8 a0[8], a1[8], b0[4], b1[4];
#pragma unroll
      for (int m = 0; m < 8; ++m) {
        const int row = wm + m * 16 + lr;
        const u16* base = &Asb[d + row * 64];
        a0[m] = *(const s16x8*)(base + (((kg)     ^ (row & 7)) << 3));
        a1[m] = *(const s16x8*)(base + (((4 + kg) ^ (row & 7)) << 3));
      }
#pragma unroll
      for (int n = 0; n < 4; ++n) {
        const int row = wn + n * 16 + lr;
        b0[n] = *(const s16x8*)(&Bsb[d + row * 64] + (((kg) ^ (row & 7)) << 3));
      }
      if (kt + 1 < kTiles) STAGE_B(kt + 1);

      __builtin_amdgcn_s_setprio(1);
#pragma unroll
      for (int m = 0; m < 8; ++m)
#pragma unroll
        for (int n = 0; n < 4; ++n)
          acc[m][n] = __builtin_amdgcn_mfma_f32_16x16x32_bf16(a0[m], b0[n], acc[m][n], 0, 0, 0);
      __builtin_amdgcn_s_setprio(0);

#pragma unroll
      for (int n = 0; n < 4; ++n) {
        const int row = wn + n * 16 + lr;
        b1[n] = *(const s16x8*)(&Bsb[d + row * 64] + (((4 + kg) ^ (row & 7)) << 3));
      }
      asm volatile("s_waitcnt lgkmcnt(0)" ::: "memory");
      __builtin_amdgcn_s_barrier();
      asm volatile("" ::: "memory");
      if (kt + 2 < kTiles) STAGE_A(kt + 2);

      __builtin_amdgcn_s_setprio(1);
#pragma unroll
      for (int m = 0; m < 8; ++m)
#pragma unroll
        for (int n = 0; n < 4; ++n)
          acc[m][n] = __builtin_amdgcn_mfma_f32_16x16x32_bf16(a1[m], b1[n], acc[m][n], 0, 0, 0);
      __builtin_amdgcn_s_setprio(0);
    }
  } else {
    // ---------------- fp8 path: kperm b128 reads (r15, 0 conflicts) ---------
    const u8* A = (const u8*)Av;
    const u8* Bp = (const u8*)Bmv;
    auto STAGE_A8 = [&](int t) {
      const int k0 = t << 6;
      u8* lds = (u8*)Asb + (t & 1) * 16384;
#pragma unroll
      for (int p = 0; p < 2; ++p) {
        const int q = p * 512 + tid;
        const int lrow = q >> 3;
        const int cp = (q & 7) ^ (lrow & 7);
        const int dr = lrow + ((cp & 4) << 5);
        GLD16(A + (size_t)(m0 + dr) * lda + k0 + ((cp & 3) << 4), lds + q * 16);
      }
    };
    auto STAGE_B8 = [&](int t) {
      const int k0 = t << 6;
      u8* lds = (u8*)Bsb + (t & 1) * 16384;
#pragma unroll
      for (int p = 0; p < 2; ++p) {
        const int q = p * 512 + tid;
        const int lrow = q >> 3;
        const int cp = (q & 7) ^ (lrow & 7);
        const int dr = lrow + ((cp & 4) << 5);
        GLD16(Bp + (size_t)(n0 + dr) * ldb + k0 + ((cp & 3) << 4), lds + q * 16);
      }
    };
    STAGE_A8(0); STAGE_B8(0); STAGE_A8(1);
    for (int kt = 0; kt < kTiles; ++kt) {
      const u8* Ad = (const u8*)Asb + (kt & 1) * 16384;
      const u8* Bd = (const u8*)Bsb + (kt & 1) * 16384;
      if (kt + 1 < kTiles) asm volatile("s_waitcnt vmcnt(2)" ::: "memory");
      else                 asm volatile("s_waitcnt vmcnt(0)" ::: "memory");
      __builtin_amdgcn_s_barrier();
      asm volatile("" ::: "memory");

      l64x2 av[8], bv[4];
#pragma unroll
      for (int m = 0; m < 8; ++m) {
        const int dd = wm + m * 16 + lr;
        const int lrow = dd & 127;
        const int q = (((dd >> 7) << 2) | kg) ^ (lrow & 7);
        av[m] = *(const l64x2*)(Ad + lrow * 128 + (q << 4));
      }
#pragma unroll
      for (int n = 0; n < 4; ++n) {
        const int dd = wn + n * 16 + lr;
        const int lrow = dd & 127;
        const int q = (((dd >> 7) << 2) | kg) ^ (lrow & 7);
        bv[n] = *(const l64x2*)(Bd + lrow * 128 + (q << 4));
      }
      if (kt + 1 < kTiles) STAGE_B8(kt + 1);

      // cluster 0 — compiler tracks ds_read->MFMA register deps
      __builtin_amdgcn_s_setprio(1);
#pragma unroll
      for (int m = 0; m < 8; ++m)
#pragma unroll
        for (int n = 0; n < 4; ++n)
          acc[m][n] = __builtin_amdgcn_mfma_f32_16x16x32_fp8_fp8(av[m][0], bv[n][0], acc[m][n], 0, 0, 0);
      __builtin_amdgcn_s_setprio(0);

      asm volatile("s_waitcnt lgkmcnt(0)" ::: "memory");  // all reads landed
      __builtin_amdgcn_s_barrier();
      asm volatile("" ::: "memory");
      if (kt + 2 < kTiles) STAGE_A8(kt + 2);              // A-region provably free

      __builtin_amdgcn_s_setprio(1);
#pragma unroll
      for (int m = 0; m < 8; ++m)
#pragma unroll
        for (int n = 0; n < 4; ++n)
          acc[m][n] = __builtin_amdgcn_mfma_f32_16x16x32_fp8_fp8(av[m][1], bv[n][1], acc[m][n], 0, 0, 0);
      __builtin_amdgcn_s_setprio(0);
    }
  }

  if (MODE == 0) {
    u16* Cptr = (u16*)Cp + (size_t)bz * (size_t)strideC;
    const u16* inp = (const u16*)res + (size_t)bz * (size_t)strideC;
    float psum = 0.f, psq = 0.f;
#pragma unroll
    for (int m = 0; m < 8; ++m) {
      const int rb = m0 + wm + m * 16 + kg * 4;
#pragma unroll
      for (int n = 0; n < 4; ++n) {
        const int col = n0 + wn + n * 16 + lr;
#pragma unroll
        for (int j = 0; j < 4; ++j) {
          const size_t idx = (size_t)(rb + j) * ldc + col;
          float v = acc[m][n][j] + bf2f(inp[idx]) + bias[rb + j];
          psum += v; psq += v * v;
          Cptr[idx] = f2bf(v);
        }
      }
    }
    for (int o = 32; o; o >>= 1) { psum += __shfl_down(psum, o); psq += __shfl_down(psq, o); }
    if (lane == 0) { rs_[wave] = psum; rq_[wave] = psq; }
    __syncthreads();
    if (tid == 0) {
      float s = 0.f, q = 0.f;
#pragma unroll
      for (int w = 0; w < 8; ++w) { s += rs_[w]; q += rq_[w]; }
      stat_part[(size_t)bz * 4 + by * 2 + bx] = make_float2(s, q);
    }
  } else if (MODE == 1) {
    u8* Cptr = (u8*)Cp;
#pragma unroll
    for (int m = 0; m < 8; ++m) {
      const int rb = m0 + wm + m * 16 + kg * 4;
#pragma unroll
      for (int n = 0; n < 4; ++n) {
        const int col = n0 + wn + n * 16 + lr;
        const float bs = bias[col];
        const int pcol = kperm(col);         // h stored K-permuted for fc2
        unsigned int p01 = cvtpk_fp8(gelu_fast(acc[m][n][0] + bs),
                                     gelu_fast(acc[m][n][1] + bs));
        unsigned int p23 = cvtpk_fp8(gelu_fast(acc[m][n][2] + bs),
                                     gelu_fast(acc[m][n][3] + bs));
        Cptr[(size_t)(rb + 0) * ldc + pcol] = (u8)(p01 & 0xff);
        Cptr[(size_t)(rb + 1) * ldc + pcol] = (u8)(p01 >> 8);
        Cptr[(size_t)(rb + 2) * ldc + pcol] = (u8)(p23 & 0xff);
        Cptr[(size_t)(rb + 3) * ldc + pcol] = (u8)(p23 >> 8);
      }
    }
  } else {
    // fc2 epilogue: out = acc + fc2_b[col] + LN2(s) computed inline.
    float* Cptr = (float*)Cp;
    const u16* sp = (const u16*)res;         // s (bf16)
    const int bb = m0 >> 9;                  // batch (tile spans one batch)
    float2 p0 = stat_part[(size_t)bb * 4 + 0];
    float2 p1 = stat_part[(size_t)bb * 4 + 1];
    float2 p2 = stat_part[(size_t)bb * 4 + 2];
    float2 p3 = stat_part[(size_t)bb * 4 + 3];
    float ssum = (p0.x + p1.x) + (p2.x + p3.x);
    float sq = (p0.y + p1.y) + (p2.y + p3.y);
    const float mu = ssum * (1.f / (float)TC);
    const float rsv = rsqrtf(sq * (1.f / (float)TC) - mu * mu + 1e-5f);
#pragma unroll
    for (int m = 0; m < 8; ++m) {
      const int rb = m0 + wm + m * 16 + kg * 4;
#pragma unroll
      for (int n = 0; n < 4; ++n) {
        const int col = n0 + wn + n * 16 + lr;
        const float bs = bias[col];
#pragma unroll
        for (int j = 0; j < 4; ++j) {
          const size_t idx = (size_t)(rb + j) * ldc + col;
          const int wi = (int)(idx & (size_t)(TC - 1));
          float x2v = (bf2f(sp[idx]) - mu) * rsv * ln2w[wi] + ln2b[wi];
          Cptr[idx] = acc[m][n][j] + bs + x2v;
        }
      }
    }
  }
}

// -------------------------------- launcher ---------------------------------

extern "C" void kernel_launch(void* const* d_in, const int* in_sizes, int n_in,
                              void* d_out, int out_size, void* d_ws, size_t ws_size,
                              hipStream_t stream) {
  const float* inputs = (const float*)d_in[0];
  const float* ln1_w  = (const float*)d_in[1];
  const float* ln1_b  = (const float*)d_in[2];
  const float* ln2_w  = (const float*)d_in[3];
  const float* ln2_b  = (const float*)d_in[4];
  const float* triu_W = (const float*)d_in[5];
  const float* triu_b = (const float*)d_in[6];
  const float* fc1_W  = (const float*)d_in[7];
  const float* fc1_b  = (const float*)d_in[8];
  const float* fc2_W  = (const float*)d_in[9];
  const float* fc2_b  = (const float*)d_in[10];
  float* out = (float*)d_out;
  (void)in_sizes; (void)n_in; (void)out_size; (void)ws_size;

  char* ws = (char*)d_ws;
  size_t off = 0;
  auto carve = [&](size_t bytes) {
    char* p = ws + off;
    off += (bytes + 255) & ~(size_t)255;
    return p;
  };
  u16* s_bf = (u16*)carve((size_t)B_ * T_ * C_ * 2);   // 67MB bf16 s
  u16* xT   = (u16*)carve((size_t)B_ * T_ * C_ * 2);   // 67MB bf16 xT
  u16* inb  = (u16*)carve((size_t)B_ * T_ * C_ * 2);   // 67MB bf16 inputs cache
  u8*  x8   = (u8*)carve((size_t)B_ * T_ * C_);        // 33MB fp8 x2 (K-permuted)
  u8*  h    = (u8*)carve((size_t)B_ * T_ * 2 * C_);    // 67MB fp8 h (K-permuted)
  u16* wmb  = (u16*)carve((size_t)T_ * T_ * 2);
  u8*  w1f8 = (u8*)carve((size_t)2 * C_ * C_);
  u8*  w2f8 = (u8*)carve((size_t)C_ * 2 * C_);
  float2* partials  = (float2*)carve(128 * 128 * sizeof(float2));
  float2* partials2 = (float2*)carve(128 * 4 * sizeof(float2));

  // 1) LN1 stats + bf16 inputs cache + all weight conversions (folded)
  reduce_stats_kernel<<<dim3(128, 128), 256, 0, stream>>>(
      inputs, partials, inb, triu_W, wmb, fc1_W, w1f8, fc2_W, w2f8);
  // 2) LN1 apply + transpose -> xT (bf16; stats inline)
  ln1_transpose_kernel<<<dim3(8, 8, 128), 256, 0, stream>>>(inb, ln1_w, ln1_b, partials, xT);
  // 3) TriU mix (bf16 MFMA): s = tril(W) @ x + triu_b + inputs + LN2 stats
  gemm_bt_kernel<0><<<512, 512, 0, stream>>>(
      wmb, xT, 512, 512, 512, s_bf, 512, triu_b, inb,
      (long long)TC, (long long)TC, partials2, nullptr, nullptr);
  // 4) LN2 apply -> x8 (fp8, K-permuted; stats inline)
  ln2_apply_kernel<<<16384, 256, 0, stream>>>(s_bf, ln2_w, ln2_b, partials2, x8);
  // 5) fc1 (fp8 MFMA) + GELU -> h (fp8, K-permuted)
  gemm_bt_kernel<1><<<1024, 512, 0, stream>>>(
      x8, w1f8, 512, 512, 512, h, 1024, fc1_b, nullptr, 0, 0, nullptr, nullptr, nullptr);
  // 6) fc2 (fp8 MFMA) + bias + inline-LN2(s) residual -> out (fp32)
  gemm_bt_kernel<2><<<512, 512, 0, stream>>>(
      h, w2f8, 1024, 1024, 1024, out, 512, fc2_b, s_bf, 0, 0, partials2, ln2_w, ln2_b);
}

// Round 18
// 335.652 us; speedup vs baseline: 1.0506x; 1.0506x over previous
//
#include <hip/hip_runtime.h>
#include <hip/hip_fp8.h>
#include <cstdint>

typedef unsigned short u16;
typedef unsigned char u8;
typedef __attribute__((ext_vector_type(8))) short s16x8;
typedef __attribute__((ext_vector_type(4))) float f32x4;
typedef __attribute__((ext_vector_type(8))) unsigned short u16x8;
typedef __attribute__((ext_vector_type(4))) unsigned short u16x4;
typedef __attribute__((ext_vector_type(2))) long l64x2;

#define B_ 128
#define T_ 512
#define C_ 512
#define TC 262144

static __device__ __forceinline__ float bf2f(u16 u) {
  union { unsigned int i; float f; } v; v.i = ((unsigned int)u) << 16; return v.f;
}
static __device__ __forceinline__ u16 f2bf(float f) {
  union { float fv; unsigned int i; } v; v.fv = f;
  unsigned int r = (v.i + 0x7FFFu + ((v.i >> 16) & 1u)) >> 16;
  return (u16)r;
}
// HW packed f32x2 -> fp8x2 (OCP e4m3 on gfx950); low 16 bits valid.
static __device__ __forceinline__ unsigned int cvtpk_fp8(float a, float b) {
  unsigned int r;
  asm volatile("v_cvt_pk_fp8_f32 %0, %1, %2" : "=v"(r) : "v"(a), "v"(b));
  return r & 0xffffu;
}
// K-axis permutation for fp8 operands: within each 64B K-tile, 16B slot j
// holds k-groups (j, j+4) -> one ds_read_b128 yields both MFMA k-halves.
static __device__ __forceinline__ int kperm(int c) {
  return (c & ~63) | (((c >> 3) & 3) << 4) | (((c >> 5) & 1) << 3) | (c & 7);
}

// x*sigmoid(2z) form of tanh-GELU (passed with absmax 0.031).
static __device__ __forceinline__ float gelu_fast(float x) {
  float x2 = x * x;
  float arg = 1.5957691216057308f * x * fmaf(0.044715f, x2, 1.0f);
  return x / (1.0f + __expf(-arg));
}

#define GLD16(gp, lp) __builtin_amdgcn_global_load_lds( \
    (const __attribute__((address_space(1))) void*)(gp), \
    (__attribute__((address_space(3))) void*)(lp), 16, 0, 0)

// -- LN1 stats pass + bf16 inputs cache + (folded) weight conversions --------
// wm (tril) bf16 plain; w1/w2 fp8 K-PERMUTED.

__global__ __launch_bounds__(256)
void reduce_stats_kernel(const float* __restrict__ X, float2* __restrict__ partials,
                         u16* __restrict__ Xb,
                         const float* __restrict__ triu_W, u16* __restrict__ wmb,
                         const float* __restrict__ fc1_W, u8* __restrict__ w1f8,
                         const float* __restrict__ fc2_W, u8* __restrict__ w2f8) {
  const int b = blockIdx.y, blk = blockIdx.x, tid = threadIdx.x;
  const size_t gi = (size_t)b * TC + (size_t)blk * 2048 + (size_t)tid * 8;
  const float* p = X + gi;
  f32x4 v0 = *(const f32x4*)p;
  f32x4 v1 = *(const f32x4*)(p + 4);
  float s = 0.f, q = 0.f;
  u16x8 ob;
#pragma unroll
  for (int i = 0; i < 4; ++i) {
    s += v0[i] + v1[i]; q += v0[i] * v0[i] + v1[i] * v1[i];
    ob[i] = f2bf(v0[i]); ob[4 + i] = f2bf(v1[i]);
  }
  *(u16x8*)(Xb + gi) = ob;

  // folded weight prep
  const int flat = (b * 128 + blk) * 256 + tid;
  if (flat < T_ * T_) {
    const int sr = flat >> 9, tcol = flat & 511;
    wmb[flat] = f2bf(tcol <= sr ? triu_W[flat] : 0.f);
  }
  if (flat < C_ * C_) {
    const int e = flat * 2;
    float2 a1 = *(const float2*)(fc1_W + e);
    float2 a2 = *(const float2*)(fc2_W + e);
    const int r1 = e >> 9,  c1 = e & 511;     // w1: 1024 rows x 512 k
    const int r2 = e >> 10, c2 = e & 1023;    // w2: 512 rows x 1024 k
    *(u16*)(w1f8 + (size_t)r1 * 512 + kperm(c1))  = (u16)cvtpk_fp8(a1.x, a1.y);
    *(u16*)(w2f8 + (size_t)r2 * 1024 + kperm(c2)) = (u16)cvtpk_fp8(a2.x, a2.y);
  }

  for (int o = 32; o; o >>= 1) { s += __shfl_down(s, o); q += __shfl_down(q, o); }
  __shared__ float ss[4], qq[4];
  if ((tid & 63) == 0) { ss[tid >> 6] = s; qq[tid >> 6] = q; }
  __syncthreads();
  if (tid == 0)
    partials[(size_t)b * 128 + blk] =
        make_float2(ss[0] + ss[1] + ss[2] + ss[3], qq[0] + qq[1] + qq[2] + qq[3]);
}

// --- LN1 apply + transpose -> xT (bf16; stats finalized inline) ------------

__global__ __launch_bounds__(256)
void ln1_transpose_kernel(const u16* __restrict__ Xb, const float* __restrict__ W,
                          const float* __restrict__ Bv, const float2* __restrict__ partials,
                          u16* __restrict__ xT) {
  const int b = blockIdx.z;
  const int t0 = blockIdx.y * 64, c0 = blockIdx.x * 64;
  const int tid = threadIdx.x;
  __shared__ u16 tile[64][72];
  __shared__ float smu, srs;

  if (tid < 64) {
    float2 p0 = partials[(size_t)b * 128 + tid];
    float2 p1 = partials[(size_t)b * 128 + 64 + tid];
    float s = p0.x + p1.x, q = p0.y + p1.y;
    for (int o = 32; o; o >>= 1) { s += __shfl_down(s, o); q += __shfl_down(q, o); }
    if (tid == 0) {
      float mean = s * (1.f / (float)TC);
      float var = q * (1.f / (float)TC) - mean * mean;
      smu = mean; srs = rsqrtf(var + 1e-5f);
    }
  }
  __syncthreads();
  const float mu = smu, rs = srs;

  const int rr = tid >> 4;
  const int cc = (tid & 15) * 4;
#pragma unroll
  for (int i = 0; i < 4; ++i) {
    const int lt = i * 16 + rr;
    const size_t wi = (size_t)(t0 + lt) * C_ + c0 + cc;
    u16x4 xa = *(const u16x4*)(Xb + (size_t)b * TC + wi);
    f32x4 w = *(const f32x4*)(W + wi);
    f32x4 bb = *(const f32x4*)(Bv + wi);
#pragma unroll
    for (int j = 0; j < 4; ++j)
      tile[lt][cc + j] = f2bf((bf2f(xa[j]) - mu) * rs * w[j] + bb[j]);
  }
  __syncthreads();
  const int c = tid >> 2;
  const int tg = (tid & 3) * 16;
  u16 buf[16];
#pragma unroll
  for (int i = 0; i < 16; ++i) buf[i] = tile[tg + i][c];
  const size_t o = (size_t)b * TC + (size_t)(c0 + c) * T_ + t0 + tg;
  u16x8 o0, o1;
#pragma unroll
  for (int i = 0; i < 8; ++i) { o0[i] = buf[i]; o1[i] = buf[8 + i]; }
  *(u16x8*)(xT + o) = o0;
  *(u16x8*)(xT + o + 8) = o1;
}

// - LN2 apply (stats4 inline): x2 bf16 (fc2 residual) + x8 fp8 (K-permuted) -

__global__ __launch_bounds__(256)
void ln2_apply_kernel(const u16* __restrict__ S, const float* __restrict__ W,
                      const float* __restrict__ Bv, const float2* __restrict__ partials2,
                      u16* __restrict__ x2, u8* __restrict__ x8) {
  const size_t i = ((size_t)blockIdx.x * 256 + threadIdx.x) * 8;
  const int b = (int)(i >> 18);
  const size_t r = i & (size_t)(TC - 1);
  float2 p0 = partials2[(size_t)b * 4 + 0];
  float2 p1 = partials2[(size_t)b * 4 + 1];
  float2 p2 = partials2[(size_t)b * 4 + 2];
  float2 p3 = partials2[(size_t)b * 4 + 3];
  float s = (p0.x + p1.x) + (p2.x + p3.x);
  float q = (p0.y + p1.y) + (p2.y + p3.y);
  const float mu = s * (1.f / (float)TC);
  const float rs = rsqrtf(q * (1.f / (float)TC) - mu * mu + 1e-5f);

  u16x8 sv = *(const u16x8*)(S + i);
  f32x4 w0 = *(const f32x4*)(W + r);
  f32x4 w1 = *(const f32x4*)(W + r + 4);
  f32x4 b0 = *(const f32x4*)(Bv + r);
  f32x4 b1 = *(const f32x4*)(Bv + r + 4);
  u16x8 o;
  float v[8];
#pragma unroll
  for (int j = 0; j < 4; ++j) {
    v[j]     = (bf2f(sv[j])     - mu) * rs * w0[j] + b0[j];
    v[4 + j] = (bf2f(sv[4 + j]) - mu) * rs * w1[j] + b1[j];
    o[j] = f2bf(v[j]); o[4 + j] = f2bf(v[4 + j]);
  }
  *(u16x8*)(x2 + i) = o;
  uint2 pk;
  pk.x = cvtpk_fp8(v[0], v[1]) | (cvtpk_fp8(v[2], v[3]) << 16);
  pk.y = cvtpk_fp8(v[4], v[5]) | (cvtpk_fp8(v[6], v[7]) << 16);
  const size_t pi = (i & ~(size_t)63) | (size_t)(((i >> 3) & 3) << 4) | (size_t)(((i >> 5) & 1) << 3);
  *(uint2*)(x8 + pi) = pk;
}

// ------- BT-layout MFMA GEMM, 256x256, BK=64, 2-barrier counted-vmcnt -------
// MODE 0 (TriU, bf16): proven r9 path (0 bank conflicts). epilogue bf16
//   s = acc + inputs_bf16 + triu_b[row], fused per-block LN2 partial stats.
// MODE 1/2 (fp8): K-permuted operands (kperm), LDS 128 rows x 128B tile,
//   chunk XOR (lrow&7) — verified conflict-free (r15). One ds_read_b128 per
//   fragment = both k-halves. lgkmcnt(0) AFTER cluster-0 (only needed before
//   the barrier protecting STAGE_A overwrite) so ds_reads overlap MFMA.
// MODE 1 epilogue: h = fp8(gelu(acc + fc1_b[col])), K-permuted.
// MODE 2 epilogue: out = acc + fc2_b[col] + x2 (bf16, coalesced).

template <int MODE>
__global__ __launch_bounds__(512, (MODE == 0) ? 1 : 2)
void gemm_bt_kernel(const void* __restrict__ Av, const void* __restrict__ Bmv,
                    int K, int lda, int ldb,
                    void* __restrict__ Cp, int ldc,
                    const float* __restrict__ bias,
                    const void* __restrict__ res,
                    long long strideB, long long strideC,
                    float2* __restrict__ stat_part) {
  constexpr int TILE_U16 = (MODE == 0) ? 16384 : 8192;
  __shared__ u16 Asb[2 * TILE_U16];
  __shared__ u16 Bsb[2 * TILE_U16];
  __shared__ float rs_[8], rq_[8];
  const int tid = threadIdx.x;

  // --- XCD-aware bijective remap (nwg % 8 == 0 for all launches) ---
  const int nwg = gridDim.x;
  const int orig = blockIdx.x;
  const int swz = (orig & 7) * (nwg >> 3) + (orig >> 3);
  int bx, by, bz;
  if (MODE == 0) { bz = swz >> 2; by = (swz >> 1) & 1; bx = swz & 1; }
  else if (MODE == 1) { bz = 0; by = swz >> 2; bx = swz & 3; }
  else { bz = 0; by = swz >> 1; bx = swz & 1; }

  const int m0 = by * 256, n0 = bx * 256;
  int kTiles = K >> 6;
  if (MODE == 0) { const int need = (by + 1) * 4; if (need < kTiles) kTiles = need; }

  const int lane = tid & 63;
  const int wave = tid >> 6;
  const int wm = (wave >> 2) * 128;   // 2 wave-rows of 128
  const int wn = (wave & 3) * 64;     // 4 wave-cols of 64
  const int lr = lane & 15;
  const int kg = lane >> 4;

  f32x4 acc[8][4];
  const f32x4 zero = {0.f, 0.f, 0.f, 0.f};
#pragma unroll
  for (int m = 0; m < 8; ++m)
#pragma unroll
    for (int n = 0; n < 4; ++n) acc[m][n] = zero;

  if (MODE == 0) {
    // ---------------- bf16 path (r9, proven) ----------------
    const u16* A = (const u16*)Av;
    const u16* Bp = (const u16*)Bmv + (size_t)bz * (size_t)strideB;
    auto STAGE_A = [&](int t) {
      const int k0 = t << 6;
      const int d = (t & 1) * 16384;
#pragma unroll
      for (int p = 0; p < 4; ++p) {
        const int q = p * 512 + tid;
        const int r = q >> 3;
        const int kcs = (q & 7) ^ (r & 7);
        GLD16(A + (size_t)(m0 + r) * lda + k0 + (kcs << 3), &Asb[d + q * 8]);
      }
    };
    auto STAGE_B = [&](int t) {
      const int k0 = t << 6;
      const int d = (t & 1) * 16384;
#pragma unroll
      for (int p = 0; p < 4; ++p) {
        const int q = p * 512 + tid;
        const int r = q >> 3;
        const int kcs = (q & 7) ^ (r & 7);
        GLD16(Bp + (size_t)(n0 + r) * ldb + k0 + (kcs << 3), &Bsb[d + q * 8]);
      }
    };
    STAGE_A(0); STAGE_B(0); STAGE_A(1);
    for (int kt = 0; kt < kTiles; ++kt) {
      const int d = (kt & 1) * 16384;
      if (kt + 1 < kTiles) asm volatile("s_waitcnt vmcnt(4)" ::: "memory");
      else                 asm volatile("s_waitcnt vmcnt(0)" ::: "memory");
      __builtin_amdgcn_s_barrier();
      asm volatile("" ::: "memory");

      s16x8 a0[8], a1[8], b0[4], b1[4];
#pragma unroll
      for (int m = 0; m < 8; ++m) {
        const int row = wm + m * 16 + lr;
        const u16* base = &Asb[d + row * 64];
        a0[m] = *(const s16x8*)(base + (((kg)     ^ (row & 7)) << 3));
        a1[m] = *(const s16x8*)(base + (((4 + kg) ^ (row & 7)) << 3));
      }
#pragma unroll
      for (int n = 0; n < 4; ++n) {
        const int row = wn + n * 16 + lr;
        b0[n] = *(const s16x8*)(&Bsb[d + row * 64] + (((kg) ^ (row & 7)) << 3));
      }
      if (kt + 1 < kTiles) STAGE_B(kt + 1);

      __builtin_amdgcn_s_setprio(1);
#pragma unroll
      for (int m = 0; m < 8; ++m)
#pragma unroll
        for (int n = 0; n < 4; ++n)
          acc[m][n] = __builtin_amdgcn_mfma_f32_16x16x32_bf16(a0[m], b0[n], acc[m][n], 0, 0, 0);
      __builtin_amdgcn_s_setprio(0);

#pragma unroll
      for (int n = 0; n < 4; ++n) {
        const int row = wn + n * 16 + lr;
        b1[n] = *(const s16x8*)(&Bsb[d + row * 64] + (((4 + kg) ^ (row & 7)) << 3));
      }
      asm volatile("s_waitcnt lgkmcnt(0)" ::: "memory");
      __builtin_amdgcn_s_barrier();
      asm volatile("" ::: "memory");
      if (kt + 2 < kTiles) STAGE_A(kt + 2);

      __builtin_amdgcn_s_setprio(1);
#pragma unroll
      for (int m = 0; m < 8; ++m)
#pragma unroll
        for (int n = 0; n < 4; ++n)
          acc[m][n] = __builtin_amdgcn_mfma_f32_16x16x32_bf16(a1[m], b1[n], acc[m][n], 0, 0, 0);
      __builtin_amdgcn_s_setprio(0);
    }
  } else {
    // ---------------- fp8 path: kperm b128 reads (r15, 0 conflicts) ---------
    const u8* A = (const u8*)Av;
    const u8* Bp = (const u8*)Bmv;
    auto STAGE_A8 = [&](int t) {
      const int k0 = t << 6;
      u8* lds = (u8*)Asb + (t & 1) * 16384;
#pragma unroll
      for (int p = 0; p < 2; ++p) {
        const int q = p * 512 + tid;
        const int lrow = q >> 3;
        const int cp = (q & 7) ^ (lrow & 7);
        const int dr = lrow + ((cp & 4) << 5);
        GLD16(A + (size_t)(m0 + dr) * lda + k0 + ((cp & 3) << 4), lds + q * 16);
      }
    };
    auto STAGE_B8 = [&](int t) {
      const int k0 = t << 6;
      u8* lds = (u8*)Bsb + (t & 1) * 16384;
#pragma unroll
      for (int p = 0; p < 2; ++p) {
        const int q = p * 512 + tid;
        const int lrow = q >> 3;
        const int cp = (q & 7) ^ (lrow & 7);
        const int dr = lrow + ((cp & 4) << 5);
        GLD16(Bp + (size_t)(n0 + dr) * ldb + k0 + ((cp & 3) << 4), lds + q * 16);
      }
    };
    STAGE_A8(0); STAGE_B8(0); STAGE_A8(1);
    for (int kt = 0; kt < kTiles; ++kt) {
      const u8* Ad = (const u8*)Asb + (kt & 1) * 16384;
      const u8* Bd = (const u8*)Bsb + (kt & 1) * 16384;
      if (kt + 1 < kTiles) asm volatile("s_waitcnt vmcnt(2)" ::: "memory");
      else                 asm volatile("s_waitcnt vmcnt(0)" ::: "memory");
      __builtin_amdgcn_s_barrier();
      asm volatile("" ::: "memory");

      l64x2 av[8], bv[4];
#pragma unroll
      for (int m = 0; m < 8; ++m) {
        const int dd = wm + m * 16 + lr;
        const int lrow = dd & 127;
        const int q = (((dd >> 7) << 2) | kg) ^ (lrow & 7);
        av[m] = *(const l64x2*)(Ad + lrow * 128 + (q << 4));
      }
#pragma unroll
      for (int n = 0; n < 4; ++n) {
        const int dd = wn + n * 16 + lr;
        const int lrow = dd & 127;
        const int q = (((dd >> 7) << 2) | kg) ^ (lrow & 7);
        bv[n] = *(const l64x2*)(Bd + lrow * 128 + (q << 4));
      }
      if (kt + 1 < kTiles) STAGE_B8(kt + 1);

      // cluster 0 — compiler tracks ds_read->MFMA register deps
      __builtin_amdgcn_s_setprio(1);
#pragma unroll
      for (int m = 0; m < 8; ++m)
#pragma unroll
        for (int n = 0; n < 4; ++n)
          acc[m][n] = __builtin_amdgcn_mfma_f32_16x16x32_fp8_fp8(av[m][0], bv[n][0], acc[m][n], 0, 0, 0);
      __builtin_amdgcn_s_setprio(0);

      asm volatile("s_waitcnt lgkmcnt(0)" ::: "memory");  // all reads landed
      __builtin_amdgcn_s_barrier();
      asm volatile("" ::: "memory");
      if (kt + 2 < kTiles) STAGE_A8(kt + 2);              // A-region provably free

      __builtin_amdgcn_s_setprio(1);
#pragma unroll
      for (int m = 0; m < 8; ++m)
#pragma unroll
        for (int n = 0; n < 4; ++n)
          acc[m][n] = __builtin_amdgcn_mfma_f32_16x16x32_fp8_fp8(av[m][1], bv[n][1], acc[m][n], 0, 0, 0);
      __builtin_amdgcn_s_setprio(0);
    }
  }

  if (MODE == 0) {
    u16* Cptr = (u16*)Cp + (size_t)bz * (size_t)strideC;
    const u16* inp = (const u16*)res + (size_t)bz * (size_t)strideC;
    float psum = 0.f, psq = 0.f;
#pragma unroll
    for (int m = 0; m < 8; ++m) {
      const int rb = m0 + wm + m * 16 + kg * 4;
#pragma unroll
      for (int n = 0; n < 4; ++n) {
        const int col = n0 + wn + n * 16 + lr;
#pragma unroll
        for (int j = 0; j < 4; ++j) {
          const size_t idx = (size_t)(rb + j) * ldc + col;
          float v = acc[m][n][j] + bf2f(inp[idx]) + bias[rb + j];
          psum += v; psq += v * v;
          Cptr[idx] = f2bf(v);
        }
      }
    }
    for (int o = 32; o; o >>= 1) { psum += __shfl_down(psum, o); psq += __shfl_down(psq, o); }
    if (lane == 0) { rs_[wave] = psum; rq_[wave] = psq; }
    __syncthreads();
    if (tid == 0) {
      float s = 0.f, q = 0.f;
#pragma unroll
      for (int w = 0; w < 8; ++w) { s += rs_[w]; q += rq_[w]; }
      stat_part[(size_t)bz * 4 + by * 2 + bx] = make_float2(s, q);
    }
  } else if (MODE == 1) {
    u8* Cptr = (u8*)Cp;
#pragma unroll
    for (int m = 0; m < 8; ++m) {
      const int rb = m0 + wm + m * 16 + kg * 4;
#pragma unroll
      for (int n = 0; n < 4; ++n) {
        const int col = n0 + wn + n * 16 + lr;
        const float bs = bias[col];
        const int pcol = kperm(col);         // h stored K-permuted for fc2
        unsigned int p01 = cvtpk_fp8(gelu_fast(acc[m][n][0] + bs),
                                     gelu_fast(acc[m][n][1] + bs));
        unsigned int p23 = cvtpk_fp8(gelu_fast(acc[m][n][2] + bs),
                                     gelu_fast(acc[m][n][3] + bs));
        Cptr[(size_t)(rb + 0) * ldc + pcol] = (u8)(p01 & 0xff);
        Cptr[(size_t)(rb + 1) * ldc + pcol] = (u8)(p01 >> 8);
        Cptr[(size_t)(rb + 2) * ldc + pcol] = (u8)(p23 & 0xff);
        Cptr[(size_t)(rb + 3) * ldc + pcol] = (u8)(p23 >> 8);
      }
    }
  } else {
    float* Cptr = (float*)Cp;
    const u16* x2p = (const u16*)res;
#pragma unroll
    for (int m = 0; m < 8; ++m) {
      const int rb = m0 + wm + m * 16 + kg * 4;
#pragma unroll
      for (int n = 0; n < 4; ++n) {
        const int col = n0 + wn + n * 16 + lr;
        const float bs = bias[col];
#pragma unroll
        for (int j = 0; j < 4; ++j) {
          const size_t idx = (size_t)(rb + j) * ldc + col;
          Cptr[idx] = acc[m][n][j] + bs + bf2f(x2p[idx]);
        }
      }
    }
  }
}

// -------------------------------- launcher ---------------------------------

extern "C" void kernel_launch(void* const* d_in, const int* in_sizes, int n_in,
                              void* d_out, int out_size, void* d_ws, size_t ws_size,
                              hipStream_t stream) {
  const float* inputs = (const float*)d_in[0];
  const float* ln1_w  = (const float*)d_in[1];
  const float* ln1_b  = (const float*)d_in[2];
  const float* ln2_w  = (const float*)d_in[3];
  const float* ln2_b  = (const float*)d_in[4];
  const float* triu_W = (const float*)d_in[5];
  const float* triu_b = (const float*)d_in[6];
  const float* fc1_W  = (const float*)d_in[7];
  const float* fc1_b  = (const float*)d_in[8];
  const float* fc2_W  = (const float*)d_in[9];
  const float* fc2_b  = (const float*)d_in[10];
  float* out = (float*)d_out;
  (void)in_sizes; (void)n_in; (void)out_size; (void)ws_size;

  char* ws = (char*)d_ws;
  size_t off = 0;
  auto carve = [&](size_t bytes) {
    char* p = ws + off;
    off += (bytes + 255) & ~(size_t)255;
    return p;
  };
  u16* s_bf = (u16*)carve((size_t)B_ * T_ * C_ * 2);   // 67MB bf16 s
  u16* xT   = (u16*)carve((size_t)B_ * T_ * C_ * 2);   // 67MB bf16 xT; reused as x2
  u16* x2   = xT;
  u16* inb  = (u16*)carve((size_t)B_ * T_ * C_ * 2);   // 67MB bf16 inputs cache
  u8*  x8   = (u8*)carve((size_t)B_ * T_ * C_);        // 33MB fp8 x2 (K-permuted)
  u8*  h    = (u8*)carve((size_t)B_ * T_ * 2 * C_);    // 67MB fp8 h (K-permuted)
  u16* wmb  = (u16*)carve((size_t)T_ * T_ * 2);
  u8*  w1f8 = (u8*)carve((size_t)2 * C_ * C_);
  u8*  w2f8 = (u8*)carve((size_t)C_ * 2 * C_);
  float2* partials  = (float2*)carve(128 * 128 * sizeof(float2));
  float2* partials2 = (float2*)carve(128 * 4 * sizeof(float2));

  // 1) LN1 stats + bf16 inputs cache + all weight conversions (folded)
  reduce_stats_kernel<<<dim3(128, 128), 256, 0, stream>>>(
      inputs, partials, inb, triu_W, wmb, fc1_W, w1f8, fc2_W, w2f8);
  // 2) LN1 apply + transpose -> xT (bf16; stats inline)
  ln1_transpose_kernel<<<dim3(8, 8, 128), 256, 0, stream>>>(inb, ln1_w, ln1_b, partials, xT);
  // 3) TriU mix (bf16 MFMA): s = tril(W) @ x + triu_b + inputs + LN2 stats
  //    (xT fully consumed here; buffer is then reused as x2)
  gemm_bt_kernel<0><<<512, 512, 0, stream>>>(
      wmb, xT, 512, 512, 512, s_bf, 512, triu_b, inb,
      (long long)TC, (long long)TC, partials2);
  // 4) LN2 apply -> x2 (bf16) + x8 (fp8, K-permuted)  (stats inline)
  ln2_apply_kernel<<<16384, 256, 0, stream>>>(s_bf, ln2_w, ln2_b, partials2, x2, x8);
  // 5) fc1 (fp8 MFMA) + GELU -> h (fp8, K-permuted)
  gemm_bt_kernel<1><<<1024, 512, 0, stream>>>(
      x8, w1f8, 512, 512, 512, h, 1024, fc1_b, nullptr, 0, 0, nullptr);
  // 6) fc2 (fp8 MFMA) + bias + x2 residual -> out (fp32)
  gemm_bt_kernel<2><<<512, 512, 0, stream>>>(
      h, w2f8, 1024, 1024, 1024, out, 512, fc2_b, x2, 0, 0, nullptr);
}